// Round 1
// 1227.350 us; speedup vs baseline: 1.1851x; 1.1851x over previous
//
#include <hip/hip_runtime.h>
#include <hip/hip_bf16.h>

// Sizes (fixed by the reference)
#define T_TOKENS 1024
#define HID      2048
#define NEXP     64
#define TOPK     8
#define MLP      768
#define NPAIR    (T_TOKENS * TOPK)   // 8192

typedef __bf16 bf16x8 __attribute__((ext_vector_type(8)));
typedef float  f32x4  __attribute__((ext_vector_type(4)));
typedef unsigned int u32x2 __attribute__((ext_vector_type(2)));
typedef unsigned int u32x4 __attribute__((ext_vector_type(4)));

#define LDK 40   // LDS row stride in shorts (16B-aligned fragment reads, 2-way-max bank aliasing)

static __device__ __forceinline__ unsigned short f2bf(float f) {
    __hip_bfloat16 h = __float2bfloat16(f);
    unsigned short u;
    __builtin_memcpy(&u, &h, sizeof(u));
    return u;
}
static __device__ __forceinline__ unsigned int pk2bf(float a, float b) {
    return (unsigned int)f2bf(a) | ((unsigned int)f2bf(b) << 16);
}

// ---------------------------------------------------------------------------
// Router: logits = hs @ router_w, top-8 per token, softmax over the 8.
// ---------------------------------------------------------------------------
__global__ __launch_bounds__(256) void router_topk_kernel(
    const float* __restrict__ hs, const float* __restrict__ rw,
    int* __restrict__ sel, float* __restrict__ wts)
{
    const int lane = threadIdx.x & 63;
    const int tg   = threadIdx.x >> 6;
    const int t    = blockIdx.x * 4 + tg;

    const float4* x4 = (const float4*)(hs + (size_t)t * HID);
    float acc = 0.f;
    for (int h4 = 0; h4 < HID / 4; ++h4) {
        float4 xv = x4[h4];
        int hb = h4 * 4 * NEXP + lane;
        acc += xv.x * rw[hb] + xv.y * rw[hb + NEXP]
             + xv.z * rw[hb + 2 * NEXP] + xv.w * rw[hb + 3 * NEXP];
    }

    float v = acc;
    float tv[TOPK]; int ti[TOPK];
    for (int i = 0; i < TOPK; ++i) {
        float m = v; int mi = lane;
        for (int off = 32; off > 0; off >>= 1) {
            float om  = __shfl_xor(m, off, 64);
            int   omi = __shfl_xor(mi, off, 64);
            if (om > m || (om == m && omi < mi)) { m = om; mi = omi; }
        }
        tv[i] = m; ti[i] = mi;
        if (lane == mi) v = -__builtin_inff();
    }
    if (lane == 0) {
        float mx = tv[0], s = 0.f, e[TOPK];
        for (int i = 0; i < TOPK; ++i) { e[i] = __expf(tv[i] - mx); s += e[i]; }
        float inv = 1.f / s;
        for (int i = 0; i < TOPK; ++i) {
            wts[t * TOPK + i] = e[i] * inv;
            sel[t * TOPK + i] = ti[i];
        }
    }
}

// ---------------------------------------------------------------------------
// Routing bookkeeping
// ---------------------------------------------------------------------------
__global__ void count_kernel(const int* __restrict__ sel, int* __restrict__ counts)
{
    int p = blockIdx.x * 256 + threadIdx.x;
    if (p < NPAIR) atomicAdd(&counts[sel[p]], 1);
}

__global__ void scan_kernel(const int* __restrict__ counts,
                            int* __restrict__ offsets, int* __restrict__ cursor)
{
    if (threadIdx.x == 0) {
        int s = 0;
        for (int e = 0; e < NEXP; ++e) { offsets[e] = s; cursor[e] = s; s += counts[e]; }
        offsets[NEXP] = s;
    }
}

__global__ void scatter_kernel(const int* __restrict__ sel,
                               int* __restrict__ cursor, int* __restrict__ rows)
{
    int p = blockIdx.x * 256 + threadIdx.x;
    if (p < NPAIR) {
        int e = sel[p];
        int pos = atomicAdd(&cursor[e], 1);
        rows[pos] = p;   // pair id; token = p>>3
    }
}

// ---------------------------------------------------------------------------
// gate/up GEMM + SiLU fused.  Block = 512 threads = 8 waves.
// Waves 0-3 compute gate (48 rows x 64 cols each), waves 4-7 compute up on
// the SAME rows/cols (acc = 48 VGPR/wave instead of 96 -> stay under the
// 128-VGPR occupancy cliff).  1-deep register prefetch, double-buffered LDS,
// raw s_barrier with lgkmcnt(0) only: global loads stay in flight across the
// barrier (vmcnt never drained to 0 in the main loop).
// ---------------------------------------------------------------------------
__global__ __launch_bounds__(512) void gateup_kernel(
    const float* __restrict__ hs, const float* __restrict__ gw,
    const float* __restrict__ uw, const int* __restrict__ offsets,
    const int* __restrict__ rows, unsigned short* __restrict__ hb)
{
    const int e  = blockIdx.y;
    const int n0 = blockIdx.x * 64;
    const int r0 = offsets[e];
    const int nrows = offsets[e + 1] - r0;
    if (nrows <= 0) return;

    // 2 buffers x (A 192*40 + G 64*40 + U 64*40) shorts = 51200 B
    __shared__ __align__(16) float smemf[12800];
    unsigned short* smem = (unsigned short*)smemf;

    const int thr  = threadIdx.x;
    const int wave = thr >> 6;
    const int lane = thr & 63;
    const int wg   = wave & 3;          // row-group 0..3 (48 rows each)
    const int isUp = wave >> 2;         // waves 4-7 do up
    const int fr   = lane & 15;
    const int fq   = lane >> 4;

    // A staging: float4 chunk per slot; slots thr, thr+512, thr+1024
    const int ar = thr >> 3;            // row 0..63 (then +64, +128)
    const int ac = (thr & 7) * 4;       // k-col in shorts (0,4,..,28)

    // W staging: thr<256 -> gate, thr>=256 -> up; pair-slot = (k2, nq)
    const int wk2 = thr & 15;           // k = 2*wk2
    const int wnq = (thr & 255) >> 4;   // n = wnq*4
    const float* wsrc = (thr >= 256 ? uw : gw)
        + (size_t)e * HID * MLP + (size_t)(2 * wk2) * MLP + n0 + wnq * 4;
    const int mofs = (thr >= 256) ? 10240 : 7680;  // U / G region (stage==compute role)

    const int NS = HID / 32;            // 64 K-steps

    for (int m0 = 0; m0 < nrows; m0 += 192) {
        // ---- hoist gather pointers (rows[] read once, not per K-step)
        const float *ap0, *ap1, *ap2;
        bool av0, av1, av2;
        {
            int gr0 = m0 + ar, gr1 = m0 + ar + 64, gr2 = m0 + ar + 128;
            av0 = gr0 < nrows; av1 = gr1 < nrows; av2 = gr2 < nrows;
            int p0 = av0 ? rows[r0 + gr0] : 0;
            int p1 = av1 ? rows[r0 + gr1] : 0;
            int p2 = av2 ? rows[r0 + gr2] : 0;
            ap0 = hs + (size_t)(p0 >> 3) * HID + ac;   // ac in shorts == floats offset/1? (ac = k-col in bf16 slots == floats here)
            ap1 = hs + (size_t)(p1 >> 3) * HID + ac;
            ap2 = hs + (size_t)(p2 >> 3) * HID + ac;
        }

        f32x4 va0, va1, va2, w0, w1;
        const f32x4 fz = (f32x4){0.f, 0.f, 0.f, 0.f};

        auto LOAD = [&](int s) {
            va0 = av0 ? *(const f32x4*)(ap0 + s * 32) : fz;
            va1 = av1 ? *(const f32x4*)(ap1 + s * 32) : fz;
            va2 = av2 ? *(const f32x4*)(ap2 + s * 32) : fz;
            const float* wp = wsrc + (size_t)s * 32 * MLP;
            w0 = *(const f32x4*)wp;
            w1 = *(const f32x4*)(wp + MLP);
        };
        auto WRITE = [&](int s) {
            unsigned short* b = smem + (s & 1) * 12800;
            u32x2 v;
            v[0] = pk2bf(va0[0], va0[1]); v[1] = pk2bf(va0[2], va0[3]);
            *(u32x2*)(b + ar * LDK + ac) = v;
            v[0] = pk2bf(va1[0], va1[1]); v[1] = pk2bf(va1[2], va1[3]);
            *(u32x2*)(b + (ar + 64) * LDK + ac) = v;
            v[0] = pk2bf(va2[0], va2[1]); v[1] = pk2bf(va2[2], va2[3]);
            *(u32x2*)(b + (ar + 128) * LDK + ac) = v;
            unsigned short* wb = b + mofs;
            #pragma unroll
            for (int i = 0; i < 4; ++i)
                *(unsigned int*)(wb + (wnq * 4 + i) * LDK + 2 * wk2) = pk2bf(w0[i], w1[i]);
        };

        f32x4 acc[3][4];
        #pragma unroll
        for (int ms = 0; ms < 3; ++ms)
            #pragma unroll
            for (int ns = 0; ns < 4; ++ns) acc[ms][ns] = fz;

        LOAD(0);
        WRITE(0);
        LOAD(1);
        asm volatile("s_waitcnt lgkmcnt(0)" ::: "memory");
        __builtin_amdgcn_s_barrier();

        for (int s = 0; s < NS; ++s) {
            const unsigned short* bb  = smem + (s & 1) * 12800;
            const unsigned short* wbb = bb + mofs;
            bf16x8 aF0, aF1, aF2, wF[4];
            #pragma unroll
            for (int ns = 0; ns < 4; ++ns)
                wF[ns] = *(const bf16x8*)(wbb + (ns * 16 + fr) * LDK + fq * 8);
            aF0 = *(const bf16x8*)(bb + (wg * 48 + fr) * LDK + fq * 8);
            aF1 = *(const bf16x8*)(bb + (wg * 48 + 16 + fr) * LDK + fq * 8);
            aF2 = *(const bf16x8*)(bb + (wg * 48 + 32 + fr) * LDK + fq * 8);

            if (s + 1 < NS) WRITE(s + 1);   // vmcnt-counted wait on LOAD(s+1) regs
            if (s + 2 < NS) LOAD(s + 2);    // in flight across the barrier + next MFMA

            const int rem = nrows - m0 - wg * 48;
            if (rem > 0) {
                #pragma unroll
                for (int ns = 0; ns < 4; ++ns)
                    acc[0][ns] = __builtin_amdgcn_mfma_f32_16x16x32_bf16(aF0, wF[ns], acc[0][ns], 0, 0, 0);
            }
            if (rem > 16) {
                #pragma unroll
                for (int ns = 0; ns < 4; ++ns)
                    acc[1][ns] = __builtin_amdgcn_mfma_f32_16x16x32_bf16(aF1, wF[ns], acc[1][ns], 0, 0, 0);
            }
            if (rem > 32) {
                #pragma unroll
                for (int ns = 0; ns < 4; ++ns)
                    acc[2][ns] = __builtin_amdgcn_mfma_f32_16x16x32_bf16(aF2, wF[ns], acc[2][ns], 0, 0, 0);
            }
            asm volatile("s_waitcnt lgkmcnt(0)" ::: "memory");
            __builtin_amdgcn_s_barrier();
        }

        // ---- epilogue: up waves export accU via LDS (stride 65: conflict-lite),
        //      gate waves combine h = silu(g)*u -> bf16 hb
        float* xb = smemf;
        if (isUp) {
            #pragma unroll
            for (int ms = 0; ms < 3; ++ms)
                #pragma unroll
                for (int i = 0; i < 4; ++i) {
                    int lrow = wg * 48 + ms * 16 + fq * 4 + i;
                    #pragma unroll
                    for (int ns = 0; ns < 4; ++ns)
                        xb[lrow * 65 + ns * 16 + fr] = acc[ms][ns][i];
                }
        }
        __syncthreads();
        if (!isUp) {
            #pragma unroll
            for (int ms = 0; ms < 3; ++ms)
                #pragma unroll
                for (int i = 0; i < 4; ++i) {
                    int lrow = wg * 48 + ms * 16 + fq * 4 + i;
                    int grow = m0 + lrow;
                    if (grow < nrows) {
                        unsigned short* drow = hb + (size_t)(r0 + grow) * MLP + n0;
                        #pragma unroll
                        for (int ns = 0; ns < 4; ++ns) {
                            float g = acc[ms][ns][i];
                            float u = xb[lrow * 65 + ns * 16 + fr];
                            float h = g * u / (1.f + __expf(-g));
                            drow[ns * 16 + fr] = f2bf(h);
                        }
                    }
                }
        }
        __syncthreads();
    }
}

// ---------------------------------------------------------------------------
// down GEMM: out[token] += w * (h_sorted @ down[e]).  Same pipeline, K=768.
// 256 threads = 4 waves, each wave 48 rows x 64 cols.
// ---------------------------------------------------------------------------
__global__ __launch_bounds__(256) void down_kernel(
    const unsigned short* __restrict__ hb, const float* __restrict__ dw,
    const int* __restrict__ offsets, const int* __restrict__ rows,
    const float* __restrict__ wts, float* __restrict__ out)
{
    const int e  = blockIdx.y;
    const int n0 = blockIdx.x * 64;
    const int r0 = offsets[e];
    const int nrows = offsets[e + 1] - r0;
    if (nrows <= 0) return;

    // 2 buffers x (A 192*40 + W 64*40) shorts = 40960 B
    __shared__ __align__(16) float smemf[10240];
    unsigned short* smem = (unsigned short*)smemf;

    const int thr  = threadIdx.x;
    const int wave = thr >> 6;
    const int lane = thr & 63;
    const int fr   = lane & 15;
    const int fq   = lane >> 4;

    // A staging: 16B bf16 chunk per slot; slots thr, thr+256, thr+512
    const int ar = thr >> 2;            // row 0..63 (then +64, +128)
    const int ac = (thr & 3) * 8;       // k-col in shorts (0,8,16,24)

    // W staging
    const int wk2 = thr & 15;           // k = 2*wk2
    const int wnq = thr >> 4;           // n = wnq*4 (0..60)
    const float* wsrc = dw + (size_t)e * MLP * HID + (size_t)(2 * wk2) * HID + n0 + wnq * 4;

    const int NS = MLP / 32;            // 24 K-steps

    for (int m0 = 0; m0 < nrows; m0 += 192) {
        const bool av0 = (m0 + ar)       < nrows;
        const bool av1 = (m0 + ar + 64)  < nrows;
        const bool av2 = (m0 + ar + 128) < nrows;
        const unsigned short* hp0 = hb + (size_t)(r0 + m0 + ar) * MLP + ac;
        const unsigned short* hp1 = hp0 + (size_t)64  * MLP;
        const unsigned short* hp2 = hp0 + (size_t)128 * MLP;

        u32x4 ua0, ua1, ua2; f32x4 w0, w1;
        const u32x4 uz = (u32x4){0u, 0u, 0u, 0u};
        const f32x4 fz = (f32x4){0.f, 0.f, 0.f, 0.f};

        auto LOAD = [&](int s) {
            ua0 = av0 ? *(const u32x4*)(hp0 + s * 32) : uz;
            ua1 = av1 ? *(const u32x4*)(hp1 + s * 32) : uz;
            ua2 = av2 ? *(const u32x4*)(hp2 + s * 32) : uz;
            const float* wp = wsrc + (size_t)s * 32 * HID;
            w0 = *(const f32x4*)wp;
            w1 = *(const f32x4*)(wp + HID);
        };
        auto WRITE = [&](int s) {
            unsigned short* b = smem + (s & 1) * 10240;
            *(u32x4*)(b + ar * LDK + ac) = ua0;
            *(u32x4*)(b + (ar + 64) * LDK + ac) = ua1;
            *(u32x4*)(b + (ar + 128) * LDK + ac) = ua2;
            unsigned short* wb = b + 7680;
            #pragma unroll
            for (int i = 0; i < 4; ++i)
                *(unsigned int*)(wb + (wnq * 4 + i) * LDK + 2 * wk2) = pk2bf(w0[i], w1[i]);
        };

        f32x4 acc[3][4];
        #pragma unroll
        for (int ms = 0; ms < 3; ++ms)
            #pragma unroll
            for (int ns = 0; ns < 4; ++ns) acc[ms][ns] = fz;

        LOAD(0);
        WRITE(0);
        LOAD(1);
        asm volatile("s_waitcnt lgkmcnt(0)" ::: "memory");
        __builtin_amdgcn_s_barrier();

        for (int s = 0; s < NS; ++s) {
            const unsigned short* bb = smem + (s & 1) * 10240;
            bf16x8 aF0, aF1, aF2, bF[4];
            #pragma unroll
            for (int ns = 0; ns < 4; ++ns)
                bF[ns] = *(const bf16x8*)(bb + 7680 + (ns * 16 + fr) * LDK + fq * 8);
            aF0 = *(const bf16x8*)(bb + (wave * 48 + fr) * LDK + fq * 8);
            aF1 = *(const bf16x8*)(bb + (wave * 48 + 16 + fr) * LDK + fq * 8);
            aF2 = *(const bf16x8*)(bb + (wave * 48 + 32 + fr) * LDK + fq * 8);

            if (s + 1 < NS) WRITE(s + 1);
            if (s + 2 < NS) LOAD(s + 2);

            const int rem = nrows - m0 - wave * 48;
            if (rem > 0) {
                #pragma unroll
                for (int ns = 0; ns < 4; ++ns)
                    acc[0][ns] = __builtin_amdgcn_mfma_f32_16x16x32_bf16(aF0, bF[ns], acc[0][ns], 0, 0, 0);
            }
            if (rem > 16) {
                #pragma unroll
                for (int ns = 0; ns < 4; ++ns)
                    acc[1][ns] = __builtin_amdgcn_mfma_f32_16x16x32_bf16(aF1, bF[ns], acc[1][ns], 0, 0, 0);
            }
            if (rem > 32) {
                #pragma unroll
                for (int ns = 0; ns < 4; ++ns)
                    acc[2][ns] = __builtin_amdgcn_mfma_f32_16x16x32_bf16(aF2, bF[ns], acc[2][ns], 0, 0, 0);
            }
            asm volatile("s_waitcnt lgkmcnt(0)" ::: "memory");
            __builtin_amdgcn_s_barrier();
        }

        // epilogue: scale by routing weight, accumulate into out[token]
        #pragma unroll
        for (int ms = 0; ms < 3; ++ms) {
            #pragma unroll
            for (int i = 0; i < 4; ++i) {
                int lrow = wave * 48 + ms * 16 + fq * 4 + i;
                int grow = m0 + lrow;
                if (grow < nrows) {
                    int p  = rows[r0 + grow];
                    float w = wts[p];
                    float* orow = out + (size_t)(p >> 3) * HID + n0;
                    #pragma unroll
                    for (int ns = 0; ns < 4; ++ns)
                        atomicAdd(orow + ns * 16 + fr, acc[ms][ns][i] * w);
                }
            }
        }
    }
}

// ---------------------------------------------------------------------------
extern "C" void kernel_launch(void* const* d_in, const int* in_sizes, int n_in,
                              void* d_out, int out_size, void* d_ws, size_t ws_size,
                              hipStream_t stream)
{
    const float* hs = (const float*)d_in[0];   // [1024, 2048]
    const float* rw = (const float*)d_in[1];   // [2048, 64]
    const float* gw = (const float*)d_in[2];   // [64, 2048, 768]
    const float* uw = (const float*)d_in[3];   // [64, 2048, 768]
    const float* dw = (const float*)d_in[4];   // [64, 768, 2048]
    float* out = (float*)d_out;                // [1024, 2048]

    char* ws = (char*)d_ws;
    int*   sel     = (int*)(ws);                         // 8192 ints
    float* wts     = (float*)(ws + 32768);               // 8192 floats
    int*   counts  = (int*)(ws + 65536);                 // 64
    int*   offsets = (int*)(ws + 65792);                 // 65
    int*   cursor  = (int*)(ws + 66304);                 // 64
    int*   rows    = (int*)(ws + 66560);                 // 8192
    unsigned short* hb = (unsigned short*)(ws + 99328);  // 8192*768 bf16 = 12.6 MB

    hipMemsetAsync(out, 0, (size_t)T_TOKENS * HID * sizeof(float), stream);
    hipMemsetAsync(counts, 0, NEXP * sizeof(int), stream);

    router_topk_kernel<<<T_TOKENS / 4, 256, 0, stream>>>(hs, rw, sel, wts);
    count_kernel<<<NPAIR / 256, 256, 0, stream>>>(sel, counts);
    scan_kernel<<<1, 64, 0, stream>>>(counts, offsets, cursor);
    scatter_kernel<<<NPAIR / 256, 256, 0, stream>>>(sel, cursor, rows);
    gateup_kernel<<<dim3(MLP / 64, NEXP), 512, 0, stream>>>(hs, gw, uw, offsets, rows, hb);
    down_kernel<<<dim3(HID / 64, NEXP), 256, 0, stream>>>(hb, dw, offsets, rows, wts, out);
}